// Round 4
// baseline (559.212 us; speedup 1.0000x reference)
//
#include <hip/hip_runtime.h>
#include <hip/hip_bf16.h>

// Problem constants
#define BDIM 4
#define SDIM 2048
#define MDIM 4
#define DDIM 2048
#define EDIM 1024
#define NTOK 8192           // B*S
#define KDIM 1024           // E
#define NPANEL 16           // D / 128
#define EPS_GATE 1.1920929e-07f
#define EPS_CONV 1e-5f
#define RSQRT_D 0.022097086912079608f   // 1/sqrt(2048)

typedef __bf16 bf16x8 __attribute__((ext_vector_type(8)));
typedef float f32x4 __attribute__((ext_vector_type(4)));
typedef unsigned short ushort8 __attribute__((ext_vector_type(8)));

__constant__ int OFFS[8] = {0, 130003, 260024, 390051, 520094, 650145, 780202, 910271};

__device__ __forceinline__ float bf2f(unsigned short u) {
  union { unsigned int i; float f; } x; x.i = ((unsigned int)u) << 16; return x.f;
}
__device__ __forceinline__ unsigned short f2bf(float f) {
  __hip_bfloat16 h = __float2bfloat16(f);
  unsigned short u; __builtin_memcpy(&u, &h, 2); return u;
}

// ---------------- gather: emb_table rows -> bf16 emb [8192][1024] ------------
__global__ __launch_bounds__(256) void k_gather(const int* __restrict__ idx,
                                                const float* __restrict__ table,
                                                unsigned short* __restrict__ embb) {
  const int tok = blockIdx.x;
  const int tid = threadIdx.x;
  const int h = tid >> 5;            // 8 heads x 32 threads
  const int e = (tid & 31) * 4;      // 4 floats per thread
  const int row = idx[tok * 8 + h] + OFFS[h];
  const float4 v = *(const float4*)(table + (size_t)row * 128 + e);
  ushort4 st;
  st.x = f2bf(v.x); st.y = f2bf(v.y); st.z = f2bf(v.z); st.w = f2bf(v.w);
  *(ushort4*)(embb + (size_t)tok * 1024 + h * 128 + e) = st;
}

// ---------------- weight convert: [w_v ; w_k] fp32 -> bf16 [10240][1024] -----
__global__ __launch_bounds__(256) void k_cvtw(const float* __restrict__ wv,
                                              const float* __restrict__ wk,
                                              unsigned short* __restrict__ Wb) {
  const size_t i = ((size_t)blockIdx.x * 256 + threadIdx.x) * 4;
  const size_t NV = (size_t)DDIM * EDIM;  // 2097152
  float4 v;
  if (i < NV) v = *(const float4*)(wv + i);
  else        v = *(const float4*)(wk + (i - NV));
  ushort4 st;
  st.x = f2bf(v.x); st.y = f2bf(v.y); st.z = f2bf(v.z); st.w = f2bf(v.w);
  *(ushort4*)(Wb + i) = st;
}

// ---------------- shared GEMM core macros (m97 structure) --------------------
#define GLDS(g, l) __builtin_amdgcn_global_load_lds(                        \
    (const __attribute__((address_space(1))) void*)(g),                    \
    (__attribute__((address_space(3))) void*)(l), 16, 0, 0)

// Stages one 128x64 bf16 tile pair + runs MFMA loop; expects surrounding fn to
// declare lA,lB,acc,lane,wave,wr,wc and row/col base pointers per K-step.
// (Written inline in each kernel below for clarity.)

// ---------------- value GEMM: Cv[8192][2048] bf16 = emb * w_v^T --------------
__global__ __launch_bounds__(256) void k_gemm_v(const unsigned short* __restrict__ A,
                                                const unsigned short* __restrict__ Bw,
                                                unsigned short* __restrict__ Cv)
{
  __shared__ __align__(16) unsigned short lA[128 * 64];
  __shared__ __align__(16) unsigned short lB[128 * 64];
  const int tid = threadIdx.x;
  const int lane = tid & 63, wave = tid >> 6;
  const int row0 = blockIdx.y * 128;
  const int col0 = blockIdx.x * 128;   // value col block (0..2047)
  const int wr = (wave >> 1) * 64, wc = (wave & 1) * 64;

  f32x4 acc[4][4] = {};

  for (int k0 = 0; k0 < KDIM; k0 += 64) {
#pragma unroll
    for (int it = 0; it < 4; ++it) {
      const int sg = wave * 4 + it;
      const int chunk = sg * 64 + lane;
      const int r = chunk >> 3;
      const int c = (chunk & 7) * 8;
      GLDS(A  + (size_t)(row0 + r) * KDIM + k0 + c, (char*)lA + sg * 1024);
      GLDS(Bw + (size_t)(col0 + r) * KDIM + k0 + c, (char*)lB + sg * 1024);
    }
    __syncthreads();
    const int lr = lane & 15;
#pragma unroll
    for (int kk = 0; kk < 2; ++kk) {
      const int lk = kk * 32 + (lane >> 4) * 8;
      bf16x8 af[4], bfr[4];
#pragma unroll
      for (int i = 0; i < 4; ++i)
        af[i] = *(const bf16x8*)(lA + (wr + i * 16 + lr) * 64 + lk);
#pragma unroll
      for (int i = 0; i < 4; ++i)
        bfr[i] = *(const bf16x8*)(lB + (wc + i * 16 + lr) * 64 + lk);
#pragma unroll
      for (int i = 0; i < 4; ++i)
#pragma unroll
        for (int j = 0; j < 4; ++j)
          acc[i][j] = __builtin_amdgcn_mfma_f32_16x16x32_bf16(af[i], bfr[j], acc[i][j], 0, 0, 0);
    }
    __syncthreads();
  }

  const int lcol = lane & 15;
  const int rbase = (lane >> 4) * 4;
#pragma unroll
  for (int i = 0; i < 4; ++i) {
#pragma unroll
    for (int j = 0; j < 4; ++j) {
      const int gr = row0 + wr + i * 16 + rbase;
      const int gc = col0 + wc + j * 16 + lcol;
      unsigned short* p = Cv + (size_t)gr * DDIM + gc;
#pragma unroll
      for (int r = 0; r < 4; ++r) p[(size_t)r * DDIM] = f2bf(acc[i][j][r]);
    }
  }
}

// ---------------- keys GEMM + fused score reductions (no keys in memory) -----
// block = (panel p, row-block r0, branch m). Computes C[128][128] = emb * w_k^T
// panel, then reduces per row: sk=sum(c^2), sd=sum(c*h*wk*wh), sh=sum(h^2).
// Writes disjoint per-panel partial slots — no atomics, deterministic.
__global__ __launch_bounds__(256) void k_gemm_k(const unsigned short* __restrict__ A,
                                                const unsigned short* __restrict__ Bw,
                                                const float* __restrict__ hidden,
                                                const float* __restrict__ norm_h,
                                                const float* __restrict__ norm_k,
                                                float* __restrict__ skP,
                                                float* __restrict__ sdP,
                                                float* __restrict__ shP)
{
  __shared__ __align__(16) unsigned short lA[128 * 64];
  __shared__ __align__(16) unsigned short lB[128 * 64];
  __shared__ float skl[2][128], sdl[2][128], shl[2][128];
  const int tid = threadIdx.x;
  const int lane = tid & 63, wave = tid >> 6;
  const int p    = blockIdx.x;          // D panel (0..15)
  const int row0 = blockIdx.y * 128;    // token block
  const int m    = blockIdx.z;          // branch
  const int wr = (wave >> 1) * 64, wc = (wave & 1) * 64;
  // B rows for this block: w_k[m] rows p*128..p*128+127 -> Wb row DDIM + m*2048 + ...
  const size_t brow0 = (size_t)DDIM + (size_t)m * DDIM + p * 128;

  f32x4 acc[4][4] = {};

  for (int k0 = 0; k0 < KDIM; k0 += 64) {
#pragma unroll
    for (int it = 0; it < 4; ++it) {
      const int sg = wave * 4 + it;
      const int chunk = sg * 64 + lane;
      const int r = chunk >> 3;
      const int c = (chunk & 7) * 8;
      GLDS(A  + (size_t)(row0 + r) * KDIM + k0 + c, (char*)lA + sg * 1024);
      GLDS(Bw + (brow0 + r) * KDIM + k0 + c, (char*)lB + sg * 1024);
    }
    __syncthreads();
    const int lr = lane & 15;
#pragma unroll
    for (int kk = 0; kk < 2; ++kk) {
      const int lk = kk * 32 + (lane >> 4) * 8;
      bf16x8 af[4], bfr[4];
#pragma unroll
      for (int i = 0; i < 4; ++i)
        af[i] = *(const bf16x8*)(lA + (wr + i * 16 + lr) * 64 + lk);
#pragma unroll
      for (int i = 0; i < 4; ++i)
        bfr[i] = *(const bf16x8*)(lB + (wc + i * 16 + lr) * 64 + lk);
#pragma unroll
      for (int i = 0; i < 4; ++i)
#pragma unroll
        for (int j = 0; j < 4; ++j)
          acc[i][j] = __builtin_amdgcn_mfma_f32_16x16x32_bf16(af[i], bfr[j], acc[i][j], 0, 0, 0);
    }
    __syncthreads();
  }

  // ---- fused score epilogue ----
  // C/D layout: col = wc + j*16 + (lane&15), row = wr + i*16 + (lane>>4)*4 + reg
  const int lcol = lane & 15;
  const int g = lane >> 4;
  const int dbase = p * 128 + wc;       // d-offset within this m's D
  float wkh[4];
#pragma unroll
  for (int j = 0; j < 4; ++j) {
    const int d = dbase + j * 16 + lcol;
    wkh[j] = norm_k[m * DDIM + d] * norm_h[m * DDIM + d];
  }
#pragma unroll
  for (int i = 0; i < 4; ++i) {
#pragma unroll
    for (int reg = 0; reg < 4; ++reg) {
      const int row = wr + i * 16 + g * 4 + reg;
      const size_t hb = ((size_t)(row0 + row) * 4 + m) * DDIM + dbase;
      float pk = 0.f, pd = 0.f, ph = 0.f;
#pragma unroll
      for (int j = 0; j < 4; ++j) {
        const float c = acc[i][j][reg];
        const float h = hidden[hb + j * 16 + lcol];
        pk += c * c;
        ph += h * h;
        pd += c * h * wkh[j];
      }
      // reduce across the 16 lanes of group g (xor of bits 0..3 stays in group)
#pragma unroll
      for (int off = 1; off < 16; off <<= 1) {
        pk += __shfl_xor(pk, off);
        pd += __shfl_xor(pd, off);
        ph += __shfl_xor(ph, off);
      }
      if (lcol == 0) {
        skl[wave & 1][row] = pk;
        sdl[wave & 1][row] = pd;
        shl[wave & 1][row] = ph;
      }
    }
  }
  __syncthreads();
  if (tid < 128) {
    const int row = tid;
    const int tok = row0 + row;
    const size_t pidx = ((size_t)tok * 4 + m) * NPANEL + p;
    skP[pidx] = skl[0][row] + skl[1][row];
    sdP[pidx] = sdl[0][row] + sdl[1][row];
    shP[pidx] = shl[0][row] + shl[1][row];
  }
}

// ---------------- alpha/gate: combine partials + msv from value --------------
__global__ __launch_bounds__(256) void k_alpha(const unsigned short* __restrict__ valueb,
                                               const float* __restrict__ skP,
                                               const float* __restrict__ sdP,
                                               const float* __restrict__ shP,
                                               float* __restrict__ gates,
                                               float* __restrict__ alphas) {
  const int tok = blockIdx.x;
  const int tid = threadIdx.x, lane = tid & 63, w = tid >> 6;
  __shared__ float red[4];

  // msv = mean(value^2) over D (256 threads x 8 bf16)
  float pv = 0.f;
  {
    const ushort8 v8 = *(const ushort8*)(valueb + (size_t)tok * DDIM + tid * 8);
#pragma unroll
    for (int t = 0; t < 8; ++t) { const float f = bf2f(v8[t]); pv += f * f; }
  }
#pragma unroll
  for (int off = 32; off > 0; off >>= 1) pv += __shfl_down(pv, off);
  if (lane == 0) red[w] = pv;
  __syncthreads();

  if (tid < 4) {
    const int m = tid;
    const float msv = (red[0] + red[1] + red[2] + red[3]) * (1.f / 2048.f);
    const size_t base = ((size_t)tok * 4 + m) * NPANEL;
    float sk = 0.f, sd = 0.f, sh = 0.f;
#pragma unroll
    for (int q = 0; q < NPANEL; ++q) {
      sk += skP[base + q]; sd += sdP[base + q]; sh += shP[base + q];
    }
    const float msk = sk * (1.f / 2048.f) + EPS_GATE;
    const float msh = sh * (1.f / 2048.f) + EPS_GATE;
    const float score = sd * rsqrtf(msk) * rsqrtf(msh) * RSQRT_D;
    const float sgn = (score > 0.f) ? 1.f : ((score < 0.f) ? -1.f : 0.f);
    const float gg = sqrtf(fmaxf(fabsf(score), 1e-6f)) * sgn;
    const float gate = 1.f / (1.f + expf(-gg));
    gates[tok * 4 + m] = gate;
    alphas[tok * 4 + m] = gate * rsqrtf(gate * gate * msv + EPS_CONV);
  }
}

// ---------------- final: one thread owns (tok, d), loops m -------------------
__global__ __launch_bounds__(256) void k_final(const float* __restrict__ hidden,
                                               const unsigned short* __restrict__ valueb,
                                               const float* __restrict__ gates,
                                               const float* __restrict__ alphas,
                                               const float* __restrict__ wcn,
                                               const float* __restrict__ cw,   // [M*D][4]
                                               float* __restrict__ outp) {
  const long lin = (long)blockIdx.x * 256 + threadIdx.x;  // (tok, d4)
  const int d4 = (int)(lin & 511);
  const int tok = (int)(lin >> 9);
  const int s = tok & (SDIM - 1);
  const int d = d4 * 4;

  float4 vj[4];
  {
    const ushort4 u = *(const ushort4*)(valueb + (size_t)tok * DDIM + d);
    vj[0] = make_float4(bf2f(u.x), bf2f(u.y), bf2f(u.z), bf2f(u.w));
  }
#pragma unroll
  for (int j = 1; j < 4; ++j) {
    if (s >= 3 * j) {
      const ushort4 u = *(const ushort4*)(valueb + (size_t)(tok - 3 * j) * DDIM + d);
      vj[j] = make_float4(bf2f(u.x), bf2f(u.y), bf2f(u.z), bf2f(u.w));
    } else vj[j] = make_float4(0.f, 0.f, 0.f, 0.f);
  }

#pragma unroll
  for (int m = 0; m < 4; ++m) {
    const float g = gates[tok * 4 + m];
    const float4 h4 = *(const float4*)(hidden + ((size_t)tok * 4 + m) * DDIM + d);
    const float4 wn = *(const float4*)(wcn + m * DDIM + d);
    float a[4];
#pragma unroll
    for (int j = 0; j < 4; ++j)
      a[j] = (s >= 3 * j) ? alphas[(tok - 3 * j) * 4 + m] : 0.f;
    float cwr[4][4];
#pragma unroll
    for (int i = 0; i < 4; ++i)
      *(float4*)cwr[i] = *(const float4*)(cw + (size_t)(m * DDIM + d + i) * 4);

    float cx = 0.f, cy = 0.f, cz = 0.f, cv = 0.f;
#pragma unroll
    for (int j = 0; j < 4; ++j) {
      const int t = 3 - j;
      const float aj = a[j];
      cx += cwr[0][t] * aj * vj[j].x;
      cy += cwr[1][t] * aj * vj[j].y;
      cz += cwr[2][t] * aj * vj[j].z;
      cv += cwr[3][t] * aj * vj[j].w;
    }
    cx *= wn.x; cy *= wn.y; cz *= wn.z; cv *= wn.w;
    cx = cx / (1.f + expf(-cx));
    cy = cy / (1.f + expf(-cy));
    cz = cz / (1.f + expf(-cz));
    cv = cv / (1.f + expf(-cv));

    float4 o;
    o.x = h4.x + g * vj[0].x + cx;
    o.y = h4.y + g * vj[0].y + cy;
    o.z = h4.z + g * vj[0].z + cz;
    o.w = h4.w + g * vj[0].w + cv;
    *(float4*)(outp + ((size_t)tok * 4 + m) * DDIM + d) = o;
  }
}

// ---------------- launcher ---------------------------------------------------
extern "C" void kernel_launch(void* const* d_in, const int* in_sizes, int n_in,
                              void* d_out, int out_size, void* d_ws, size_t ws_size,
                              hipStream_t stream) {
  const int*   hash_idx = (const int*)d_in[0];
  const float* hidden   = (const float*)d_in[1];
  const float* table    = (const float*)d_in[2];
  const float* w_v      = (const float*)d_in[3];
  const float* w_k      = (const float*)d_in[4];
  const float* norm_h   = (const float*)d_in[5];
  const float* norm_k   = (const float*)d_in[6];
  const float* wcn      = (const float*)d_in[7];
  const float* cw       = (const float*)d_in[8];
  float* outp = (float*)d_out;
  char* ws = (char*)d_ws;

  // workspace layout (bytes)
  unsigned short* embb  = (unsigned short*)(ws + 0);          // 16,777,216
  unsigned short* Wb    = (unsigned short*)(ws + 16777216);   // 20,971,520
  unsigned short* value = (unsigned short*)(ws + 37748736);   // 33,554,432
  float*          skP   = (float*)(ws + 71303168);            // 8192*4*16*4 = 2,097,152
  float*          sdP   = (float*)(ws + 73400320);            // 2,097,152
  float*          shP   = (float*)(ws + 75497472);            // 2,097,152
  float*          gates = (float*)(ws + 77594624);            // 131,072
  float*          alphas= (float*)(ws + 77725696);            // 131,072 (end ~77.9 MB)

  k_gather<<<NTOK, 256, 0, stream>>>(hash_idx, table, embb);
  k_cvtw<<<10240, 256, 0, stream>>>(w_v, w_k, Wb);
  dim3 gv(DDIM / 128, NTOK / 128);           // (16, 64)
  k_gemm_v<<<gv, 256, 0, stream>>>(embb, Wb, value);
  dim3 gk(NPANEL, NTOK / 128, MDIM);         // (16, 64, 4)
  k_gemm_k<<<gk, 256, 0, stream>>>(embb, Wb, hidden, norm_h, norm_k, skP, sdP, shP);
  k_alpha<<<NTOK, 256, 0, stream>>>(value, skP, sdP, shP, gates, alphas);
  k_final<<<(NTOK * DDIM / 4) / 256, 256, 0, stream>>>(hidden, value, gates, alphas, wcn, cw, outp);
}

// Round 6
// 509.831 us; speedup vs baseline: 1.0969x; 1.0969x over previous
//
#include <hip/hip_runtime.h>
#include <hip/hip_bf16.h>

// Problem constants
#define BDIM 4
#define SDIM 2048
#define MDIM 4
#define DDIM 2048
#define EDIM 1024
#define NTOK 8192           // B*S
#define NGEMM 10240         // D + M*D  (value cols + keys cols)
#define KDIM 1024           // E
#define NKT 16              // K-tiles of BK=64
#define EPS_GATE 1.1920929e-07f
#define EPS_CONV 1e-5f
#define RSQRT_D 0.022097086912079608f   // 1/sqrt(2048)

typedef __bf16 bf16x8 __attribute__((ext_vector_type(8)));
typedef float f32x4 __attribute__((ext_vector_type(4)));
typedef unsigned short ushort8 __attribute__((ext_vector_type(8)));

__constant__ int OFFS[8] = {0, 130003, 260024, 390051, 520094, 650145, 780202, 910271};

__device__ __forceinline__ float bf2f(unsigned short u) {
  union { unsigned int i; float f; } x; x.i = ((unsigned int)u) << 16; return x.f;
}
__device__ __forceinline__ unsigned short f2bf(float f) {
  __hip_bfloat16 h = __float2bfloat16(f);
  unsigned short u; __builtin_memcpy(&u, &h, 2); return u;
}

// ---------------- gather: emb_table rows -> bf16 emb [8192][1024] ------------
__global__ __launch_bounds__(256) void k_gather(const int* __restrict__ idx,
                                                const float* __restrict__ table,
                                                unsigned short* __restrict__ embb) {
  const int tok = blockIdx.x;
  const int tid = threadIdx.x;
  const int h = tid >> 5;
  const int e = (tid & 31) * 4;
  const int row = idx[tok * 8 + h] + OFFS[h];
  const float4 v = *(const float4*)(table + (size_t)row * 128 + e);
  ushort4 st;
  st.x = f2bf(v.x); st.y = f2bf(v.y); st.z = f2bf(v.z); st.w = f2bf(v.w);
  *(ushort4*)(embb + (size_t)tok * 1024 + h * 128 + e) = st;
}

// ---------------- weight convert: [w_v ; w_k] fp32 -> bf16 [10240][1024] -----
__global__ __launch_bounds__(256) void k_cvtw(const float* __restrict__ wv,
                                              const float* __restrict__ wk,
                                              unsigned short* __restrict__ Wb) {
  const size_t i = ((size_t)blockIdx.x * 256 + threadIdx.x) * 4;
  const size_t NV = (size_t)DDIM * EDIM;
  float4 v;
  if (i < NV) v = *(const float4*)(wv + i);
  else        v = *(const float4*)(wk + (i - NV));
  ushort4 st;
  st.x = f2bf(v.x); st.y = f2bf(v.y); st.z = f2bf(v.z); st.w = f2bf(v.w);
  *(ushort4*)(Wb + i) = st;
}

// ---------------- GEMM: 256x256 tile, BK=64, 8-phase counted-vmcnt schedule --
// Guide §5 8-phase template (T3+T4), no swizzle (m198 variant).
// LDS: A region ushort [0,32768) = 4 slots x 8192; B region [32768,65536).
// slot(kt, half) = (kt&1)*2 + half.
// Phases per kt (snake): P1(A-lo,B-lo) P2(A-lo,B-hi) P3(A-hi,B-hi) P4(A-hi,B-lo).
// Stage: P1:A1(kt+1), P2:A0(kt+2), P3:B0(kt+2), P4:B1(kt+2); vmcnt(6) @P4.
#define GLDS(g, l) __builtin_amdgcn_global_load_lds(                        \
    (const __attribute__((address_space(1))) void*)(g),                    \
    (__attribute__((address_space(3))) void*)(l), 16, 0, 0)

#define BARR() __builtin_amdgcn_s_barrier()
#define LGK0() asm volatile("s_waitcnt lgkmcnt(0)" ::: "memory")
#define VM6()  asm volatile("s_waitcnt vmcnt(6)" ::: "memory")
#define VM0()  asm volatile("s_waitcnt vmcnt(0)" ::: "memory")
#define SB0()  __builtin_amdgcn_sched_barrier(0)

__global__ __launch_bounds__(512, 2) void k_gemm(const unsigned short* __restrict__ A,
                                                 const unsigned short* __restrict__ Bw,
                                                 unsigned short* __restrict__ Cv,  // [8192][2048]
                                                 unsigned short* __restrict__ Ck)  // [8192][8192]
{
  __shared__ __align__(1024) unsigned short lds[65536];  // A: [0,32768), B: [32768,65536)
  const int tid = threadIdx.x;
  const int lane = tid & 63, wave = tid >> 6;
  const int wm = wave >> 2;          // 0..1
  const int wn = wave & 3;           // 0..3
  const int row0 = blockIdx.y * 256;
  const int col0 = blockIdx.x * 256;
  const int lr = lane & 15;
  const int lk = (lane >> 4) * 8;

  f32x4 acc[8][4] = {};   // [mf][nf]; mf>=4 -> row half1, nf>=2 -> col half1
  bf16x8 aa[4][2];        // current A half-set [mf-in-half][ks]
  bf16x8 bb[4][2];        // full B set [nf][ks]

  // stage one granule (128 rows x 64 k) of `src` rows rowbase..+127, K-tile kt,
  // into LDS at ushort offset gbase (wave-uniform dest; HW adds lane*16B).
#define STG(src, rowbase, kt, gbase)                                           \
  { _Pragma("unroll") for (int l = 0; l < 2; ++l) {                            \
      const int cb = l * 512 + wave * 64;                                      \
      const int chunk = cb + lane;                                             \
      GLDS((src) + (size_t)((rowbase) + (chunk >> 3)) * KDIM + (kt) * 64 +     \
               (chunk & 7) * 8,                                                \
           (char*)lds + (gbase) * 2 + cb * 16);                                \
  } }

#define LDA(gbase)                                                             \
  { _Pragma("unroll") for (int a = 0; a < 4; ++a)                              \
    _Pragma("unroll") for (int ks = 0; ks < 2; ++ks)                           \
      aa[a][ks] = *(const bf16x8*)(lds + (gbase) + (wm * 64 + a * 16 + lr) * 64 + ks * 32 + lk); }

#define LDB(gbase, n0)                                                         \
  { _Pragma("unroll") for (int n = 0; n < 2; ++n)                              \
    _Pragma("unroll") for (int ks = 0; ks < 2; ++ks)                           \
      bb[(n0) + n][ks] = *(const bf16x8*)(lds + 32768 + (gbase) + (wn * 32 + n * 16 + lr) * 64 + ks * 32 + lk); }

#define MM(mfb, nfb)                                                           \
  { __builtin_amdgcn_s_setprio(1);                                             \
    _Pragma("unroll") for (int a = 0; a < 4; ++a)                              \
    _Pragma("unroll") for (int n = 0; n < 2; ++n)                              \
    _Pragma("unroll") for (int ks = 0; ks < 2; ++ks)                           \
      acc[(mfb) + a][(nfb) + n] = __builtin_amdgcn_mfma_f32_16x16x32_bf16(     \
          aa[a][ks], bb[(nfb) + n][ks], acc[(mfb) + a][(nfb) + n], 0, 0, 0);   \
    __builtin_amdgcn_s_setprio(0); }

  // ---- prologue: A0(0),B0(0),B1(0),A1(0) then A0(1),B0(1),B1(1) ----
  // (B granules live at +32768 ushorts — THE round-5 fix)
  STG(A,  row0 +   0, 0, 0 * 8192);                 // A0(0) slotA0
  STG(Bw, col0 +   0, 0, 32768 + 0 * 8192);         // B0(0) slotB0
  STG(Bw, col0 + 128, 0, 32768 + 1 * 8192);         // B1(0) slotB1
  STG(A,  row0 + 128, 0, 1 * 8192);                 // A1(0) slotA1
  STG(A,  row0 +   0, 1, 2 * 8192);                 // A0(1) slotA2
  STG(Bw, col0 +   0, 1, 32768 + 2 * 8192);         // B0(1) slotB2
  STG(Bw, col0 + 128, 1, 32768 + 3 * 8192);         // B1(1) slotB3
  VM6();                                            // 4 oldest granules landed
  BARR(); SB0();

  for (int kt = 0; kt < NKT; ++kt) {
    const int sA = (kt & 1) * 2;               // this kt's base slot
    const int sN1 = ((kt + 1) & 1) * 2;        // next kt's base slot
    // ---- P1: read A-lo + B-lo, compute (mf0-3 x nf0-1) ----
    LDA(sA * 8192);
    LDB(sA * 8192, 0);
    if (kt + 1 < NKT) STG(A, row0 + 128, kt + 1, (sN1 + 1) * 8192);       // A1(kt+1)
    BARR(); LGK0(); SB0();
    MM(0, 0);
    BARR(); SB0();
    // ---- P2: read B-hi, compute (mf0-3 x nf2-3) ----
    LDB((sA + 1) * 8192, 2);
    if (kt + 2 < NKT) STG(A, row0 + 0, kt + 2, sA * 8192);                // A0(kt+2)
    BARR(); LGK0(); SB0();
    MM(0, 2);
    BARR(); SB0();
    // ---- P3: read A-hi, compute (mf4-7 x nf2-3) ----
    LDA((sA + 1) * 8192);
    if (kt + 2 < NKT) STG(Bw, col0 + 0, kt + 2, 32768 + sA * 8192);       // B0(kt+2)
    BARR(); LGK0(); SB0();
    MM(4, 2);
    BARR(); SB0();
    // ---- P4: no reads, compute (mf4-7 x nf0-1) ----
    if (kt + 2 < NKT) STG(Bw, col0 + 128, kt + 2, 32768 + (sA + 1) * 8192); // B1(kt+2)
    if (kt < NKT - 1) { if (kt == NKT - 2) { VM0(); } else { VM6(); } }
    BARR(); LGK0(); SB0();
    MM(4, 0);
    BARR(); SB0();
  }

  // ---- epilogue: bf16 stores; value block (col0<2048) vs keys block ----
  const int rb = (lane >> 4) * 4;
#pragma unroll
  for (int mf = 0; mf < 8; ++mf) {
#pragma unroll
    for (int nf = 0; nf < 4; ++nf) {
      const int grow = row0 + (mf >> 2) * 128 + wm * 64 + (mf & 3) * 16 + rb;
      const int gcol = col0 + (nf >> 1) * 128 + wn * 32 + (nf & 1) * 16 + lr;
      if (col0 < DDIM) {
        unsigned short* p = Cv + (size_t)grow * DDIM + gcol;
#pragma unroll
        for (int r = 0; r < 4; ++r) p[(size_t)r * DDIM] = f2bf(acc[mf][nf][r]);
      } else {
        unsigned short* p = Ck + (size_t)grow * 8192 + (gcol - DDIM);
#pragma unroll
        for (int r = 0; r < 4; ++r) p[(size_t)r * 8192] = f2bf(acc[mf][nf][r]);
      }
    }
  }
}

// ---------------- score/gate: per (token, m) -> gate, alpha ------------------
__global__ __launch_bounds__(256) void k_score(const float* __restrict__ hidden,
                                               const unsigned short* __restrict__ valueb,
                                               const unsigned short* __restrict__ keysb,
                                               const float* __restrict__ norm_h,
                                               const float* __restrict__ norm_k,
                                               float* __restrict__ gates,
                                               float* __restrict__ alphas) {
  const int tok = blockIdx.x;
  const int tid = threadIdx.x, lane = tid & 63, m = tid >> 6;
  __shared__ float smv[4];

  float pv = 0.f;
  {
    const ushort8 v8 = *(const ushort8*)(valueb + (size_t)tok * DDIM + (m * 64 + lane) * 8);
#pragma unroll
    for (int t = 0; t < 8; ++t) { const float f = bf2f(v8[t]); pv += f * f; }
  }

  const float4* hrow = (const float4*)(hidden + ((size_t)tok * 4 + m) * DDIM);
  const ushort4* krow = (const ushort4*)(keysb + (size_t)tok * 8192 + (size_t)m * DDIM);
  const float4* wkr = (const float4*)(norm_k + m * DDIM);
  const float4* whr = (const float4*)(norm_h + m * DDIM);
  float sk = 0.f, sh = 0.f, sd = 0.f;
#pragma unroll
  for (int i = 0; i < 8; ++i) {
    const int d4 = i * 64 + lane;
    const float4 h = hrow[d4];
    const float4 a = wkr[d4];
    const float4 b = whr[d4];
    const ushort4 ku = krow[d4];
    const float kx = bf2f(ku.x), ky = bf2f(ku.y), kz = bf2f(ku.z), kw = bf2f(ku.w);
    sk += kx * kx + ky * ky + kz * kz + kw * kw;
    sh += h.x * h.x + h.y * h.y + h.z * h.z + h.w * h.w;
    sd += kx * h.x * a.x * b.x + ky * h.y * a.y * b.y + kz * h.z * a.z * b.z + kw * h.w * a.w * b.w;
  }
#pragma unroll
  for (int off = 32; off > 0; off >>= 1) {
    pv += __shfl_down(pv, off);
    sk += __shfl_down(sk, off);
    sh += __shfl_down(sh, off);
    sd += __shfl_down(sd, off);
  }
  if (lane == 0) smv[m] = pv;
  __syncthreads();
  if (lane == 0) {
    const float msv = (smv[0] + smv[1] + smv[2] + smv[3]) * (1.f / 2048.f);
    const float msk = sk * (1.f / 2048.f) + EPS_GATE;
    const float msh = sh * (1.f / 2048.f) + EPS_GATE;
    const float score = sd * rsqrtf(msk) * rsqrtf(msh) * RSQRT_D;
    const float sgn = (score > 0.f) ? 1.f : ((score < 0.f) ? -1.f : 0.f);
    const float g = sqrtf(fmaxf(fabsf(score), 1e-6f)) * sgn;
    const float gate = 1.f / (1.f + expf(-g));
    gates[tok * 4 + m] = gate;
    alphas[tok * 4 + m] = gate * rsqrtf(gate * gate * msv + EPS_CONV);
  }
}

// ---------------- final: one thread owns (tok, d), loops m -------------------
__global__ __launch_bounds__(256) void k_final(const float* __restrict__ hidden,
                                               const unsigned short* __restrict__ valueb,
                                               const float* __restrict__ gates,
                                               const float* __restrict__ alphas,
                                               const float* __restrict__ wcn,
                                               const float* __restrict__ cw,   // [M*D][4]
                                               float* __restrict__ outp) {
  const long lin = (long)blockIdx.x * 256 + threadIdx.x;  // (tok, d4)
  const int d4 = (int)(lin & 511);
  const int tok = (int)(lin >> 9);
  const int s = tok & (SDIM - 1);
  const int d = d4 * 4;

  float4 vj[4];
  {
    const ushort4 u = *(const ushort4*)(valueb + (size_t)tok * DDIM + d);
    vj[0] = make_float4(bf2f(u.x), bf2f(u.y), bf2f(u.z), bf2f(u.w));
  }
#pragma unroll
  for (int j = 1; j < 4; ++j) {
    if (s >= 3 * j) {
      const ushort4 u = *(const ushort4*)(valueb + (size_t)(tok - 3 * j) * DDIM + d);
      vj[j] = make_float4(bf2f(u.x), bf2f(u.y), bf2f(u.z), bf2f(u.w));
    } else vj[j] = make_float4(0.f, 0.f, 0.f, 0.f);
  }

#pragma unroll
  for (int m = 0; m < 4; ++m) {
    const float g = gates[tok * 4 + m];
    const float4 h4 = *(const float4*)(hidden + ((size_t)tok * 4 + m) * DDIM + d);
    const float4 wn = *(const float4*)(wcn + m * DDIM + d);
    float a[4];
#pragma unroll
    for (int j = 0; j < 4; ++j)
      a[j] = (s >= 3 * j) ? alphas[(tok - 3 * j) * 4 + m] : 0.f;
    float cwr[4][4];
#pragma unroll
    for (int i = 0; i < 4; ++i)
      *(float4*)cwr[i] = *(const float4*)(cw + (size_t)(m * DDIM + d + i) * 4);

    float cx = 0.f, cy = 0.f, cz = 0.f, cv = 0.f;
#pragma unroll
    for (int j = 0; j < 4; ++j) {
      const int t = 3 - j;
      const float aj = a[j];
      cx += cwr[0][t] * aj * vj[j].x;
      cy += cwr[1][t] * aj * vj[j].y;
      cz += cwr[2][t] * aj * vj[j].z;
      cv += cwr[3][t] * aj * vj[j].w;
    }
    cx *= wn.x; cy *= wn.y; cz *= wn.z; cv *= wn.w;
    cx = cx / (1.f + expf(-cx));
    cy = cy / (1.f + expf(-cy));
    cz = cz / (1.f + expf(-cz));
    cv = cv / (1.f + expf(-cv));

    float4 o;
    o.x = h4.x + g * vj[0].x + cx;
    o.y = h4.y + g * vj[0].y + cy;
    o.z = h4.z + g * vj[0].z + cz;
    o.w = h4.w + g * vj[0].w + cv;
    *(float4*)(outp + ((size_t)tok * 4 + m) * DDIM + d) = o;
  }
}

// ---------------- launcher ---------------------------------------------------
extern "C" void kernel_launch(void* const* d_in, const int* in_sizes, int n_in,
                              void* d_out, int out_size, void* d_ws, size_t ws_size,
                              hipStream_t stream) {
  const int*   hash_idx = (const int*)d_in[0];
  const float* hidden   = (const float*)d_in[1];
  const float* table    = (const float*)d_in[2];
  const float* w_v      = (const float*)d_in[3];
  const float* w_k      = (const float*)d_in[4];
  const float* norm_h   = (const float*)d_in[5];
  const float* norm_k   = (const float*)d_in[6];
  const float* wcn      = (const float*)d_in[7];
  const float* cw       = (const float*)d_in[8];
  float* outp = (float*)d_out;
  char* ws = (char*)d_ws;

  // workspace layout (bytes)
  unsigned short* embb  = (unsigned short*)(ws + 0);          // 16,777,216
  unsigned short* Wb    = (unsigned short*)(ws + 16777216);   // 20,971,520
  unsigned short* value = (unsigned short*)(ws + 37748736);   // 33,554,432
  unsigned short* keysb = (unsigned short*)(ws + 71303168);   // 134,217,728
  float*          gates = (float*)(ws + 205520896);           // 131,072
  float*          alphas= (float*)(ws + 205651968);           // 131,072

  k_gather<<<NTOK, 256, 0, stream>>>(hash_idx, table, embb);
  k_cvtw<<<10240, 256, 0, stream>>>(w_v, w_k, Wb);
  dim3 gg(NGEMM / 256, NTOK / 256);  // (40, 32)
  k_gemm<<<gg, 512, 0, stream>>>(embb, Wb, value, keysb);
  k_score<<<NTOK, 256, 0, stream>>>(hidden, value, keysb, norm_h, norm_k, gates, alphas);
  k_final<<<(NTOK * DDIM / 4) / 256, 256, 0, stream>>>(hidden, value, gates, alphas, wcn, cw, outp);
}

// Round 7
// 465.051 us; speedup vs baseline: 1.2025x; 1.0963x over previous
//
#include <hip/hip_runtime.h>
#include <hip/hip_bf16.h>

// Problem constants
#define BDIM 4
#define SDIM 2048
#define MDIM 4
#define DDIM 2048
#define EDIM 1024
#define NTOK 8192           // B*S
#define NGEMM 10240         // D + M*D  (value cols + keys cols)
#define KDIM 1024           // E
#define NKT 16              // K-tiles of BK=64
#define EPS_GATE 1.1920929e-07f
#define EPS_CONV 1e-5f
#define RSQRT_D 0.022097086912079608f   // 1/sqrt(2048)

typedef __bf16 bf16x8 __attribute__((ext_vector_type(8)));
typedef float f32x4 __attribute__((ext_vector_type(4)));
typedef unsigned short ushort8 __attribute__((ext_vector_type(8)));

__constant__ int OFFS[8] = {0, 130003, 260024, 390051, 520094, 650145, 780202, 910271};

__device__ __forceinline__ float bf2f(unsigned short u) {
  union { unsigned int i; float f; } x; x.i = ((unsigned int)u) << 16; return x.f;
}
__device__ __forceinline__ unsigned short f2bf(float f) {
  __hip_bfloat16 h = __float2bfloat16(f);
  unsigned short u; __builtin_memcpy(&u, &h, 2); return u;
}

// ---------------- gather: emb_table rows -> bf16 emb [8192][1024] ------------
__global__ __launch_bounds__(256) void k_gather(const int* __restrict__ idx,
                                                const float* __restrict__ table,
                                                unsigned short* __restrict__ embb) {
  const int tok = blockIdx.x;
  const int tid = threadIdx.x;
  const int h = tid >> 5;
  const int e = (tid & 31) * 4;
  const int row = idx[tok * 8 + h] + OFFS[h];
  const float4 v = *(const float4*)(table + (size_t)row * 128 + e);
  ushort4 st;
  st.x = f2bf(v.x); st.y = f2bf(v.y); st.z = f2bf(v.z); st.w = f2bf(v.w);
  *(ushort4*)(embb + (size_t)tok * 1024 + h * 128 + e) = st;
}

// ---------------- weight convert: [w_v ; w_k] fp32 -> bf16 [10240][1024] -----
__global__ __launch_bounds__(256) void k_cvtw(const float* __restrict__ wv,
                                              const float* __restrict__ wk,
                                              unsigned short* __restrict__ Wb) {
  const size_t i = ((size_t)blockIdx.x * 256 + threadIdx.x) * 4;
  const size_t NV = (size_t)DDIM * EDIM;
  float4 v;
  if (i < NV) v = *(const float4*)(wv + i);
  else        v = *(const float4*)(wk + (i - NV));
  ushort4 st;
  st.x = f2bf(v.x); st.y = f2bf(v.y); st.z = f2bf(v.z); st.w = f2bf(v.w);
  *(ushort4*)(Wb + i) = st;
}

// ---------------- GEMM: 256x256 tile, BK=64, 8-phase counted-vmcnt schedule --
// Guide §5 template (T3+T4) + T2 XOR-swizzle (both-sides: pre-swizzled global
// source, linear LDS dest, swizzled ds_read) + T1 XCD block swizzle.
// LDS: A region ushort [0,32768) = 4 slots x 8192; B region [32768,65536).
// slot(kt, half) = (kt&1)*2 + half.
// Phases per kt (snake): P1(A-lo,B-lo) P2(A-lo,B-hi) P3(A-hi,B-hi) P4(A-hi,B-lo).
// Stage: P1:A1(kt+1), P2:A0(kt+2), P3:B0(kt+2), P4:B1(kt+2); vmcnt(6) @P4.
#define GLDS(g, l) __builtin_amdgcn_global_load_lds(                        \
    (const __attribute__((address_space(1))) void*)(g),                    \
    (__attribute__((address_space(3))) void*)(l), 16, 0, 0)

#define BARR() __builtin_amdgcn_s_barrier()
#define LGK0() asm volatile("s_waitcnt lgkmcnt(0)" ::: "memory")
#define VM6()  asm volatile("s_waitcnt vmcnt(6)" ::: "memory")
#define VM0()  asm volatile("s_waitcnt vmcnt(0)" ::: "memory")
#define SB0()  __builtin_amdgcn_sched_barrier(0)

__global__ __launch_bounds__(512, 2) void k_gemm(const unsigned short* __restrict__ A,
                                                 const unsigned short* __restrict__ Bw,
                                                 unsigned short* __restrict__ Cv,  // [8192][2048]
                                                 unsigned short* __restrict__ Ck)  // [8192][8192]
{
  __shared__ __align__(1024) unsigned short lds[65536];  // A: [0,32768), B: [32768,65536)
  const int tid = threadIdx.x;
  const int lane = tid & 63, wave = tid >> 6;
  const int wm = wave >> 2;          // 0..1
  const int wn = wave & 3;           // 0..3
  // T1: XCD-aware bijective block swizzle (nwg=1280, 1280%8==0)
  const int bid = blockIdx.y * gridDim.x + blockIdx.x;
  const int cpx = (gridDim.x * gridDim.y) >> 3;       // 160
  const int swz = (bid & 7) * cpx + (bid >> 3);
  const int row0 = (swz / gridDim.x) * 256;
  const int col0 = (swz % gridDim.x) * 256;
  const int lr = lane & 15;
  const int lg = lane >> 4;          // 16B-chunk group 0..3

  f32x4 acc[8][4] = {};   // [mf][nf]; mf>=4 -> row half1, nf>=2 -> col half1
  bf16x8 aa[4][2];        // current A half-set [mf-in-half][ks]
  bf16x8 bb[4][2];        // full B set [nf][ks]

  // T2 staging: LDS dest linear (HW: uniform base + lane*16B); global source
  // chunk pre-swizzled by c ^= (row&7) so a swizzled ds_read sees linear K.
#define STG(src, rowbase, kt, gbase)                                           \
  { _Pragma("unroll") for (int l = 0; l < 2; ++l) {                            \
      const int cb = l * 512 + wave * 64;                                      \
      const int chunk = cb + lane;                                             \
      const int rr = chunk >> 3;                                               \
      const int cc = (chunk & 7) ^ (rr & 7);                                   \
      GLDS((src) + (size_t)((rowbase) + rr) * KDIM + (kt) * 64 + cc * 8,       \
           (char*)lds + (gbase) * 2 + cb * 16);                                \
  } }

  // T2 read: chunk' = (ks*4 + lg) ^ (row&7); row&7 == lr&7 for 16-aligned rows
#define LDA(gbase)                                                             \
  { _Pragma("unroll") for (int a = 0; a < 4; ++a)                              \
    _Pragma("unroll") for (int ks = 0; ks < 2; ++ks)                           \
      aa[a][ks] = *(const bf16x8*)(lds + (gbase) +                             \
          (wm * 64 + a * 16 + lr) * 64 + (((ks * 4 + lg) ^ (lr & 7)) * 8)); }

#define LDB(gbase, n0)                                                         \
  { _Pragma("unroll") for (int n = 0; n < 2; ++n)                              \
    _Pragma("unroll") for (int ks = 0; ks < 2; ++ks)                           \
      bb[(n0) + n][ks] = *(const bf16x8*)(lds + 32768 + (gbase) +              \
          (wn * 32 + n * 16 + lr) * 64 + (((ks * 4 + lg) ^ (lr & 7)) * 8)); }

#define MM(mfb, nfb)                                                           \
  { __builtin_amdgcn_s_setprio(1);                                             \
    _Pragma("unroll") for (int a = 0; a < 4; ++a)                              \
    _Pragma("unroll") for (int n = 0; n < 2; ++n)                              \
    _Pragma("unroll") for (int ks = 0; ks < 2; ++ks)                           \
      acc[(mfb) + a][(nfb) + n] = __builtin_amdgcn_mfma_f32_16x16x32_bf16(     \
          aa[a][ks], bb[(nfb) + n][ks], acc[(mfb) + a][(nfb) + n], 0, 0, 0);   \
    __builtin_amdgcn_s_setprio(0); }

  // ---- prologue: A0(0),B0(0),B1(0),A1(0) then A0(1),B0(1),B1(1) ----
  STG(A,  row0 +   0, 0, 0 * 8192);                 // A0(0)
  STG(Bw, col0 +   0, 0, 32768 + 0 * 8192);         // B0(0)
  STG(Bw, col0 + 128, 0, 32768 + 1 * 8192);         // B1(0)
  STG(A,  row0 + 128, 0, 1 * 8192);                 // A1(0)
  STG(A,  row0 +   0, 1, 2 * 8192);                 // A0(1)
  STG(Bw, col0 +   0, 1, 32768 + 2 * 8192);         // B0(1)
  STG(Bw, col0 + 128, 1, 32768 + 3 * 8192);         // B1(1)
  VM6();                                            // 4 oldest granules landed
  BARR(); SB0();

  for (int kt = 0; kt < NKT; ++kt) {
    const int sA = (kt & 1) * 2;               // this kt's base slot
    const int sN1 = ((kt + 1) & 1) * 2;        // next kt's base slot
    // ---- P1: read A-lo + B-lo, compute (mf0-3 x nf0-1) ----
    LDA(sA * 8192);
    LDB(sA * 8192, 0);
    if (kt + 1 < NKT) STG(A, row0 + 128, kt + 1, (sN1 + 1) * 8192);       // A1(kt+1)
    BARR(); LGK0(); SB0();
    MM(0, 0);
    BARR(); SB0();
    // ---- P2: read B-hi, compute (mf0-3 x nf2-3) ----
    LDB((sA + 1) * 8192, 2);
    if (kt + 2 < NKT) STG(A, row0 + 0, kt + 2, sA * 8192);                // A0(kt+2)
    BARR(); LGK0(); SB0();
    MM(0, 2);
    BARR(); SB0();
    // ---- P3: read A-hi, compute (mf4-7 x nf2-3) ----
    LDA((sA + 1) * 8192);
    if (kt + 2 < NKT) STG(Bw, col0 + 0, kt + 2, 32768 + sA * 8192);       // B0(kt+2)
    BARR(); LGK0(); SB0();
    MM(4, 2);
    BARR(); SB0();
    // ---- P4: no reads, compute (mf4-7 x nf0-1) ----
    if (kt + 2 < NKT) STG(Bw, col0 + 128, kt + 2, 32768 + (sA + 1) * 8192); // B1(kt+2)
    if (kt < NKT - 1) { if (kt == NKT - 2) { VM0(); } else { VM6(); } }
    BARR(); LGK0(); SB0();
    MM(4, 0);
    BARR(); SB0();
  }

  // ---- epilogue: bf16 stores; value block (col0<2048) vs keys block ----
  const int rb = (lane >> 4) * 4;
#pragma unroll
  for (int mf = 0; mf < 8; ++mf) {
#pragma unroll
    for (int nf = 0; nf < 4; ++nf) {
      const int grow = row0 + (mf >> 2) * 128 + wm * 64 + (mf & 3) * 16 + rb;
      const int gcol = col0 + (nf >> 1) * 128 + wn * 32 + (nf & 1) * 16 + lr;
      if (col0 < DDIM) {
        unsigned short* p = Cv + (size_t)grow * DDIM + gcol;
#pragma unroll
        for (int r = 0; r < 4; ++r) p[(size_t)r * DDIM] = f2bf(acc[mf][nf][r]);
      } else {
        unsigned short* p = Ck + (size_t)grow * 8192 + (gcol - DDIM);
#pragma unroll
        for (int r = 0; r < 4; ++r) p[(size_t)r * 8192] = f2bf(acc[mf][nf][r]);
      }
    }
  }
}

// ---------------- score/gate: per (token, m) -> gate, alpha ------------------
__global__ __launch_bounds__(256) void k_score(const float* __restrict__ hidden,
                                               const unsigned short* __restrict__ valueb,
                                               const unsigned short* __restrict__ keysb,
                                               const float* __restrict__ norm_h,
                                               const float* __restrict__ norm_k,
                                               float* __restrict__ gates,
                                               float* __restrict__ alphas) {
  const int tok = blockIdx.x;
  const int tid = threadIdx.x, lane = tid & 63, m = tid >> 6;
  __shared__ float smv[4];

  float pv = 0.f;
  {
    const ushort8 v8 = *(const ushort8*)(valueb + (size_t)tok * DDIM + (m * 64 + lane) * 8);
#pragma unroll
    for (int t = 0; t < 8; ++t) { const float f = bf2f(v8[t]); pv += f * f; }
  }

  const float4* hrow = (const float4*)(hidden + ((size_t)tok * 4 + m) * DDIM);
  const ushort4* krow = (const ushort4*)(keysb + (size_t)tok * 8192 + (size_t)m * DDIM);
  const float4* wkr = (const float4*)(norm_k + m * DDIM);
  const float4* whr = (const float4*)(norm_h + m * DDIM);
  float sk = 0.f, sh = 0.f, sd = 0.f;
#pragma unroll
  for (int i = 0; i < 8; ++i) {
    const int d4 = i * 64 + lane;
    const float4 h = hrow[d4];
    const float4 a = wkr[d4];
    const float4 b = whr[d4];
    const ushort4 ku = krow[d4];
    const float kx = bf2f(ku.x), ky = bf2f(ku.y), kz = bf2f(ku.z), kw = bf2f(ku.w);
    sk += kx * kx + ky * ky + kz * kz + kw * kw;
    sh += h.x * h.x + h.y * h.y + h.z * h.z + h.w * h.w;
    sd += kx * h.x * a.x * b.x + ky * h.y * a.y * b.y + kz * h.z * a.z * b.z + kw * h.w * a.w * b.w;
  }
#pragma unroll
  for (int off = 32; off > 0; off >>= 1) {
    pv += __shfl_down(pv, off);
    sk += __shfl_down(sk, off);
    sh += __shfl_down(sh, off);
    sd += __shfl_down(sd, off);
  }
  if (lane == 0) smv[m] = pv;
  __syncthreads();
  if (lane == 0) {
    const float msv = (smv[0] + smv[1] + smv[2] + smv[3]) * (1.f / 2048.f);
    const float msk = sk * (1.f / 2048.f) + EPS_GATE;
    const float msh = sh * (1.f / 2048.f) + EPS_GATE;
    const float score = sd * rsqrtf(msk) * rsqrtf(msh) * RSQRT_D;
    const float sgn = (score > 0.f) ? 1.f : ((score < 0.f) ? -1.f : 0.f);
    const float g = sqrtf(fmaxf(fabsf(score), 1e-6f)) * sgn;
    const float gate = 1.f / (1.f + expf(-g));
    gates[tok * 4 + m] = gate;
    alphas[tok * 4 + m] = gate * rsqrtf(gate * gate * msv + EPS_CONV);
  }
}

// ---------------- final: one thread owns (tok, d), loops m -------------------
__global__ __launch_bounds__(256) void k_final(const float* __restrict__ hidden,
                                               const unsigned short* __restrict__ valueb,
                                               const float* __restrict__ gates,
                                               const float* __restrict__ alphas,
                                               const float* __restrict__ wcn,
                                               const float* __restrict__ cw,   // [M*D][4]
                                               float* __restrict__ outp) {
  const long lin = (long)blockIdx.x * 256 + threadIdx.x;  // (tok, d4)
  const int d4 = (int)(lin & 511);
  const int tok = (int)(lin >> 9);
  const int s = tok & (SDIM - 1);
  const int d = d4 * 4;

  float4 vj[4];
  {
    const ushort4 u = *(const ushort4*)(valueb + (size_t)tok * DDIM + d);
    vj[0] = make_float4(bf2f(u.x), bf2f(u.y), bf2f(u.z), bf2f(u.w));
  }
#pragma unroll
  for (int j = 1; j < 4; ++j) {
    if (s >= 3 * j) {
      const ushort4 u = *(const ushort4*)(valueb + (size_t)(tok - 3 * j) * DDIM + d);
      vj[j] = make_float4(bf2f(u.x), bf2f(u.y), bf2f(u.z), bf2f(u.w));
    } else vj[j] = make_float4(0.f, 0.f, 0.f, 0.f);
  }

#pragma unroll
  for (int m = 0; m < 4; ++m) {
    const float g = gates[tok * 4 + m];
    const float4 h4 = *(const float4*)(hidden + ((size_t)tok * 4 + m) * DDIM + d);
    const float4 wn = *(const float4*)(wcn + m * DDIM + d);
    float a[4];
#pragma unroll
    for (int j = 0; j < 4; ++j)
      a[j] = (s >= 3 * j) ? alphas[(tok - 3 * j) * 4 + m] : 0.f;
    float cwr[4][4];
#pragma unroll
    for (int i = 0; i < 4; ++i)
      *(float4*)cwr[i] = *(const float4*)(cw + (size_t)(m * DDIM + d + i) * 4);

    float cx = 0.f, cy = 0.f, cz = 0.f, cv = 0.f;
#pragma unroll
    for (int j = 0; j < 4; ++j) {
      const int t = 3 - j;
      const float aj = a[j];
      cx += cwr[0][t] * aj * vj[j].x;
      cy += cwr[1][t] * aj * vj[j].y;
      cz += cwr[2][t] * aj * vj[j].z;
      cv += cwr[3][t] * aj * vj[j].w;
    }
    cx *= wn.x; cy *= wn.y; cz *= wn.z; cv *= wn.w;
    cx = cx / (1.f + expf(-cx));
    cy = cy / (1.f + expf(-cy));
    cz = cz / (1.f + expf(-cz));
    cv = cv / (1.f + expf(-cv));

    float4 o;
    o.x = h4.x + g * vj[0].x + cx;
    o.y = h4.y + g * vj[0].y + cy;
    o.z = h4.z + g * vj[0].z + cz;
    o.w = h4.w + g * vj[0].w + cv;
    *(float4*)(outp + ((size_t)tok * 4 + m) * DDIM + d) = o;
  }
}

// ---------------- launcher ---------------------------------------------------
extern "C" void kernel_launch(void* const* d_in, const int* in_sizes, int n_in,
                              void* d_out, int out_size, void* d_ws, size_t ws_size,
                              hipStream_t stream) {
  const int*   hash_idx = (const int*)d_in[0];
  const float* hidden   = (const float*)d_in[1];
  const float* table    = (const float*)d_in[2];
  const float* w_v      = (const float*)d_in[3];
  const float* w_k      = (const float*)d_in[4];
  const float* norm_h   = (const float*)d_in[5];
  const float* norm_k   = (const float*)d_in[6];
  const float* wcn      = (const float*)d_in[7];
  const float* cw       = (const float*)d_in[8];
  float* outp = (float*)d_out;
  char* ws = (char*)d_ws;

  // workspace layout (bytes)
  unsigned short* embb  = (unsigned short*)(ws + 0);          // 16,777,216
  unsigned short* Wb    = (unsigned short*)(ws + 16777216);   // 20,971,520
  unsigned short* value = (unsigned short*)(ws + 37748736);   // 33,554,432
  unsigned short* keysb = (unsigned short*)(ws + 71303168);   // 134,217,728
  float*          gates = (float*)(ws + 205520896);           // 131,072
  float*          alphas= (float*)(ws + 205651968);           // 131,072

  k_gather<<<NTOK, 256, 0, stream>>>(hash_idx, table, embb);
  k_cvtw<<<10240, 256, 0, stream>>>(w_v, w_k, Wb);
  dim3 gg(NGEMM / 256, NTOK / 256);  // (40, 32)
  k_gemm<<<gg, 512, 0, stream>>>(embb, Wb, value, keysb);
  k_score<<<NTOK, 256, 0, stream>>>(hidden, value, keysb, norm_h, norm_k, gates, alphas);
  k_final<<<(NTOK * DDIM / 4) / 256, 256, 0, stream>>>(hidden, value, gates, alphas, wcn, cw, outp);
}

// Round 8
// 420.448 us; speedup vs baseline: 1.3300x; 1.1061x over previous
//
#include <hip/hip_runtime.h>
#include <hip/hip_bf16.h>

// Problem constants
#define BDIM 4
#define SDIM 2048
#define MDIM 4
#define DDIM 2048
#define EDIM 1024
#define NTOK 8192           // B*S
#define NGEMM 10240         // D + M*D
#define KDIM 1024           // E
#define NKT 16              // K-tiles of BK=64
#define NPAN 8              // 256-col panels per branch
#define EPS_GATE 1.1920929e-07f
#define EPS_CONV 1e-5f
#define RSQRT_D 0.022097086912079608f   // 1/sqrt(2048)

typedef __bf16 bf16x8 __attribute__((ext_vector_type(8)));
typedef float f32x4 __attribute__((ext_vector_type(4)));
typedef unsigned short ushort8 __attribute__((ext_vector_type(8)));

__constant__ int OFFS[8] = {0, 130003, 260024, 390051, 520094, 650145, 780202, 910271};

__device__ __forceinline__ float bf2f(unsigned short u) {
  union { unsigned int i; float f; } x; x.i = ((unsigned int)u) << 16; return x.f;
}
__device__ __forceinline__ unsigned short f2bf(float f) {
  __hip_bfloat16 h = __float2bfloat16(f);
  unsigned short u; __builtin_memcpy(&u, &h, 2); return u;
}

// ---------------- gather: emb_table rows -> bf16 emb [8192][1024] ------------
__global__ __launch_bounds__(256) void k_gather(const int* __restrict__ idx,
                                                const float* __restrict__ table,
                                                unsigned short* __restrict__ embb) {
  const int tok = blockIdx.x;
  const int tid = threadIdx.x;
  const int h = tid >> 5;
  const int e = (tid & 31) * 4;
  const int row = idx[tok * 8 + h] + OFFS[h];
  const float4 v = *(const float4*)(table + (size_t)row * 128 + e);
  ushort4 st;
  st.x = f2bf(v.x); st.y = f2bf(v.y); st.z = f2bf(v.z); st.w = f2bf(v.w);
  *(ushort4*)(embb + (size_t)tok * 1024 + h * 128 + e) = st;
}

// ---------------- weight convert: [w_v ; w_k] fp32 -> bf16 [10240][1024] -----
__global__ __launch_bounds__(256) void k_cvtw(const float* __restrict__ wv,
                                              const float* __restrict__ wk,
                                              unsigned short* __restrict__ Wb) {
  const size_t i = ((size_t)blockIdx.x * 256 + threadIdx.x) * 4;
  const size_t NV = (size_t)DDIM * EDIM;
  float4 v;
  if (i < NV) v = *(const float4*)(wv + i);
  else        v = *(const float4*)(wk + (i - NV));
  ushort4 st;
  st.x = f2bf(v.x); st.y = f2bf(v.y); st.z = f2bf(v.z); st.w = f2bf(v.w);
  *(ushort4*)(Wb + i) = st;
}

// ---------------- GEMM: 256x256 tile, 8-phase counted-vmcnt + fused score ----
// T3+T4+T2+T1 as round 7. Keys cols are never stored: the epilogue stages the
// hidden tile through the (now-free) 128KB LDS with coalesced float4 loads and
// reduces sk/sd/sh per row into disjoint per-panel partial slots (no atomics).
#define GLDS(g, l) __builtin_amdgcn_global_load_lds(                        \
    (const __attribute__((address_space(1))) void*)(g),                    \
    (__attribute__((address_space(3))) void*)(l), 16, 0, 0)

#define BARR() __builtin_amdgcn_s_barrier()
#define LGK0() asm volatile("s_waitcnt lgkmcnt(0)" ::: "memory")
#define VM6()  asm volatile("s_waitcnt vmcnt(6)" ::: "memory")
#define VM0()  asm volatile("s_waitcnt vmcnt(0)" ::: "memory")
#define SB0()  __builtin_amdgcn_sched_barrier(0)

__global__ __launch_bounds__(512, 1) void k_gemm(const unsigned short* __restrict__ A,
                                                 const unsigned short* __restrict__ Bw,
                                                 const float* __restrict__ hidden,
                                                 const float* __restrict__ norm_h,
                                                 const float* __restrict__ norm_k,
                                                 unsigned short* __restrict__ Cv,  // [8192][2048]
                                                 float* __restrict__ skP,          // [8192][4][8]
                                                 float* __restrict__ sdP,
                                                 float* __restrict__ shP)
{
  __shared__ __align__(1024) unsigned short lds[65536];  // A: [0,32768), B: [32768,65536)
  __shared__ float redk[2][128][4], redd[2][128][4], redh[2][128][4];  // 12KB
  const int tid = threadIdx.x;
  const int lane = tid & 63, wave = tid >> 6;
  const int wm = wave >> 2;          // 0..1
  const int wn = wave & 3;           // 0..3
  // T1: XCD-aware bijective block swizzle (nwg=1280, 1280%8==0)
  const int bid = blockIdx.y * gridDim.x + blockIdx.x;
  const int cpx = (gridDim.x * gridDim.y) >> 3;       // 160
  const int swz = (bid & 7) * cpx + (bid >> 3);
  const int row0 = (swz / gridDim.x) * 256;
  const int col0 = (swz % gridDim.x) * 256;
  const int lr = lane & 15;
  const int lg = lane >> 4;

  f32x4 acc[8][4] = {};
  bf16x8 aa[4][2];
  bf16x8 bb[4][2];

#define STG(src, rowbase, kt, gbase)                                           \
  { _Pragma("unroll") for (int l = 0; l < 2; ++l) {                            \
      const int cb = l * 512 + wave * 64;                                      \
      const int chunk = cb + lane;                                             \
      const int rr = chunk >> 3;                                               \
      const int cc = (chunk & 7) ^ (rr & 7);                                   \
      GLDS((src) + (size_t)((rowbase) + rr) * KDIM + (kt) * 64 + cc * 8,       \
           (char*)lds + (gbase) * 2 + cb * 16);                                \
  } }

#define LDA(gbase)                                                             \
  { _Pragma("unroll") for (int a = 0; a < 4; ++a)                              \
    _Pragma("unroll") for (int ks = 0; ks < 2; ++ks)                           \
      aa[a][ks] = *(const bf16x8*)(lds + (gbase) +                             \
          (wm * 64 + a * 16 + lr) * 64 + (((ks * 4 + lg) ^ (lr & 7)) * 8)); }

#define LDB(gbase, n0)                                                         \
  { _Pragma("unroll") for (int n = 0; n < 2; ++n)                              \
    _Pragma("unroll") for (int ks = 0; ks < 2; ++ks)                           \
      bb[(n0) + n][ks] = *(const bf16x8*)(lds + 32768 + (gbase) +              \
          (wn * 32 + n * 16 + lr) * 64 + (((ks * 4 + lg) ^ (lr & 7)) * 8)); }

#define MM(mfb, nfb)                                                           \
  { __builtin_amdgcn_s_setprio(1);                                             \
    _Pragma("unroll") for (int a = 0; a < 4; ++a)                              \
    _Pragma("unroll") for (int n = 0; n < 2; ++n)                              \
    _Pragma("unroll") for (int ks = 0; ks < 2; ++ks)                           \
      acc[(mfb) + a][(nfb) + n] = __builtin_amdgcn_mfma_f32_16x16x32_bf16(     \
          aa[a][ks], bb[(nfb) + n][ks], acc[(mfb) + a][(nfb) + n], 0, 0, 0);   \
    __builtin_amdgcn_s_setprio(0); }

  // ---- prologue ----
  STG(A,  row0 +   0, 0, 0 * 8192);
  STG(Bw, col0 +   0, 0, 32768 + 0 * 8192);
  STG(Bw, col0 + 128, 0, 32768 + 1 * 8192);
  STG(A,  row0 + 128, 0, 1 * 8192);
  STG(A,  row0 +   0, 1, 2 * 8192);
  STG(Bw, col0 +   0, 1, 32768 + 2 * 8192);
  STG(Bw, col0 + 128, 1, 32768 + 3 * 8192);
  VM6();
  BARR(); SB0();

  for (int kt = 0; kt < NKT; ++kt) {
    const int sA = (kt & 1) * 2;
    const int sN1 = ((kt + 1) & 1) * 2;
    LDA(sA * 8192);
    LDB(sA * 8192, 0);
    if (kt + 1 < NKT) STG(A, row0 + 128, kt + 1, (sN1 + 1) * 8192);
    BARR(); LGK0(); SB0();
    MM(0, 0);
    BARR(); SB0();
    LDB((sA + 1) * 8192, 2);
    if (kt + 2 < NKT) STG(A, row0 + 0, kt + 2, sA * 8192);
    BARR(); LGK0(); SB0();
    MM(0, 2);
    BARR(); SB0();
    LDA((sA + 1) * 8192);
    if (kt + 2 < NKT) STG(Bw, col0 + 0, kt + 2, 32768 + sA * 8192);
    BARR(); LGK0(); SB0();
    MM(4, 2);
    BARR(); SB0();
    if (kt + 2 < NKT) STG(Bw, col0 + 128, kt + 2, 32768 + (sA + 1) * 8192);
    if (kt < NKT - 1) { if (kt == NKT - 2) { VM0(); } else { VM6(); } }
    BARR(); LGK0(); SB0();
    MM(4, 0);
    BARR(); SB0();
  }

  if (col0 < DDIM) {
    // ---- value block: store bf16 ----
#pragma unroll
    for (int mf = 0; mf < 8; ++mf) {
#pragma unroll
      for (int nf = 0; nf < 4; ++nf) {
        const int grow = row0 + (mf >> 2) * 128 + wm * 64 + (mf & 3) * 16 + (lane >> 4) * 4;
        const int gcol = col0 + (nf >> 1) * 128 + wn * 32 + (nf & 1) * 16 + lr;
        unsigned short* p = Cv + (size_t)grow * DDIM + gcol;
#pragma unroll
        for (int r = 0; r < 4; ++r) p[(size_t)r * DDIM] = f2bf(acc[mf][nf][r]);
      }
    }
  } else {
    // ---- keys block: fused score reductions via LDS-staged hidden ----
    const int m = (col0 - DDIM) >> 11;
    const int dbase = (col0 - DDIM) & (DDIM - 1);
    const int pan = dbase >> 8;
    float* hl = (float*)lds;                       // 128 x 256 fp32 = 128KB
    float wkh[4];
#pragma unroll
    for (int nf = 0; nf < 4; ++nf) {
      const int cl = (nf >> 1) * 128 + wn * 32 + (nf & 1) * 16 + lr;
      wkh[nf] = norm_k[m * DDIM + dbase + cl] * norm_h[m * DDIM + dbase + cl];
    }
#pragma unroll
    for (int h = 0; h < 2; ++h) {
      BARR();  // previous half's hl reads (or main-loop LDS reads) complete
      // stage 128x256 fp32 hidden half-tile, fully coalesced
#pragma unroll
      for (int i = 0; i < 16; ++i) {
        const int idx = i * 512 + tid;             // float4 index (8192 total)
        const int rl = idx >> 6;
        const int c4 = idx & 63;
        ((float4*)hl)[idx] = *(const float4*)(hidden +
            ((size_t)(row0 + h * 128 + rl) * 4 + m) * DDIM + dbase + c4 * 4);
      }
      BARR();
#pragma unroll
      for (int mf = 0; mf < 4; ++mf) {             // mf within half h
#pragma unroll
        for (int r = 0; r < 4; ++r) {
          const int rl = wm * 64 + mf * 16 + (lane >> 4) * 4 + r;
          const int amf = h * 4 + mf;
          float pk = 0.f, pd = 0.f, ph = 0.f;
#pragma unroll
          for (int nf = 0; nf < 4; ++nf) {
            const int cl = (nf >> 1) * 128 + wn * 32 + (nf & 1) * 16 + lr;
            const float kv = acc[amf][nf][r];
            const float hv = hl[rl * 256 + cl];
            pk += kv * kv; ph += hv * hv; pd += kv * hv * wkh[nf];
          }
#pragma unroll
          for (int off = 1; off < 16; off <<= 1) {
            pk += __shfl_xor(pk, off);
            pd += __shfl_xor(pd, off);
            ph += __shfl_xor(ph, off);
          }
          if (lr == 0) {
            redk[h][rl][wn] = pk; redd[h][rl][wn] = pd; redh[h][rl][wn] = ph;
          }
        }
      }
    }
    BARR();
    if (tid < 256) {
      const int h = tid >> 7, rl = tid & 127;
      const int tok = row0 + h * 128 + rl;
      const size_t pidx = ((size_t)tok * 4 + m) * NPAN + pan;
      skP[pidx] = redk[h][rl][0] + redk[h][rl][1] + redk[h][rl][2] + redk[h][rl][3];
      sdP[pidx] = redd[h][rl][0] + redd[h][rl][1] + redd[h][rl][2] + redd[h][rl][3];
      shP[pidx] = redh[h][rl][0] + redh[h][rl][1] + redh[h][rl][2] + redh[h][rl][3];
    }
  }
}

// ---------------- alpha/gate: combine partials + msv from value --------------
__global__ __launch_bounds__(256) void k_alpha(const unsigned short* __restrict__ valueb,
                                               const float* __restrict__ skP,
                                               const float* __restrict__ sdP,
                                               const float* __restrict__ shP,
                                               float* __restrict__ gates,
                                               float* __restrict__ alphas) {
  const int tok = blockIdx.x;
  const int tid = threadIdx.x, lane = tid & 63, w = tid >> 6;
  __shared__ float red[4];

  float pv = 0.f;
  {
    const ushort8 v8 = *(const ushort8*)(valueb + (size_t)tok * DDIM + tid * 8);
#pragma unroll
    for (int t = 0; t < 8; ++t) { const float f = bf2f(v8[t]); pv += f * f; }
  }
#pragma unroll
  for (int off = 32; off > 0; off >>= 1) pv += __shfl_down(pv, off);
  if (lane == 0) red[w] = pv;
  __syncthreads();

  if (tid < 4) {
    const int m = tid;
    const float msv = (red[0] + red[1] + red[2] + red[3]) * (1.f / 2048.f);
    const size_t base = ((size_t)tok * 4 + m) * NPAN;
    float sk = 0.f, sd = 0.f, sh = 0.f;
#pragma unroll
    for (int q = 0; q < NPAN; ++q) {
      sk += skP[base + q]; sd += sdP[base + q]; sh += shP[base + q];
    }
    const float msk = sk * (1.f / 2048.f) + EPS_GATE;
    const float msh = sh * (1.f / 2048.f) + EPS_GATE;
    const float score = sd * rsqrtf(msk) * rsqrtf(msh) * RSQRT_D;
    const float sgn = (score > 0.f) ? 1.f : ((score < 0.f) ? -1.f : 0.f);
    const float gg = sqrtf(fmaxf(fabsf(score), 1e-6f)) * sgn;
    const float gate = 1.f / (1.f + expf(-gg));
    gates[tok * 4 + m] = gate;
    alphas[tok * 4 + m] = gate * rsqrtf(gate * gate * msv + EPS_CONV);
  }
}

// ---------------- final: thread owns (4-token group, d4); cw regs reused -----
__global__ __launch_bounds__(256) void k_final(const float* __restrict__ hidden,
                                               const unsigned short* __restrict__ valueb,
                                               const float* __restrict__ gates,
                                               const float* __restrict__ alphas,
                                               const float* __restrict__ wcn,
                                               const float* __restrict__ cw,   // [M*D][4]
                                               float* __restrict__ outp) {
  const int lin = blockIdx.x * 256 + threadIdx.x;   // (grp, d4)
  const int d4 = lin & 511;
  const int grp = lin >> 9;
  const int tokbase = grp * 4;          // groups never cross sequence bounds
  const int sbase = tokbase & (SDIM - 1);
  const int d = d4 * 4;

  // 13 distinct tap rows: tokbase-9 .. tokbase+3  (ri = t - 3j + 9)
  float4 vrow[13];
#pragma unroll
  for (int ri = 0; ri < 13; ++ri) {
    const int off = ri - 9;
    if (sbase + off >= 0) {
      const ushort4 u = *(const ushort4*)(valueb + (size_t)(tokbase + off) * DDIM + d);
      vrow[ri] = make_float4(bf2f(u.x), bf2f(u.y), bf2f(u.z), bf2f(u.w));
    } else vrow[ri] = make_float4(0.f, 0.f, 0.f, 0.f);
  }

#pragma unroll
  for (int m = 0; m < 4; ++m) {
    float cwr[4][4];
#pragma unroll
    for (int i = 0; i < 4; ++i)
      *(float4*)cwr[i] = *(const float4*)(cw + (size_t)(m * DDIM + d + i) * 4);
    const float4 wn = *(const float4*)(wcn + m * DDIM + d);
    float al[13];
#pragma unroll
    for (int ri = 0; ri < 13; ++ri) {
      const int off = ri - 9;
      al[ri] = (sbase + off >= 0) ? alphas[(tokbase + off) * 4 + m] : 0.f;
    }
#pragma unroll
    for (int t = 0; t < 4; ++t) {
      const int tok = tokbase + t;
      const float g = gates[tok * 4 + m];
      const float4 h4 = *(const float4*)(hidden + ((size_t)tok * 4 + m) * DDIM + d);
      float cx = 0.f, cy = 0.f, cz = 0.f, cv = 0.f;
#pragma unroll
      for (int j = 0; j < 4; ++j) {
        const int ri = t + 9 - 3 * j;
        const float aj = al[ri];
        const int tt = 3 - j;
        cx += cwr[0][tt] * aj * vrow[ri].x;
        cy += cwr[1][tt] * aj * vrow[ri].y;
        cz += cwr[2][tt] * aj * vrow[ri].z;
        cv += cwr[3][tt] * aj * vrow[ri].w;
      }
      cx *= wn.x; cy *= wn.y; cz *= wn.z; cv *= wn.w;
      cx = cx / (1.f + expf(-cx));
      cy = cy / (1.f + expf(-cy));
      cz = cz / (1.f + expf(-cz));
      cv = cv / (1.f + expf(-cv));
      const int ri0 = t + 9;
      float4 o;
      o.x = h4.x + g * vrow[ri0].x + cx;
      o.y = h4.y + g * vrow[ri0].y + cy;
      o.z = h4.z + g * vrow[ri0].z + cz;
      o.w = h4.w + g * vrow[ri0].w + cv;
      *(float4*)(outp + ((size_t)tok * 4 + m) * DDIM + d) = o;
    }
  }
}

// ---------------- launcher ---------------------------------------------------
extern "C" void kernel_launch(void* const* d_in, const int* in_sizes, int n_in,
                              void* d_out, int out_size, void* d_ws, size_t ws_size,
                              hipStream_t stream) {
  const int*   hash_idx = (const int*)d_in[0];
  const float* hidden   = (const float*)d_in[1];
  const float* table    = (const float*)d_in[2];
  const float* w_v      = (const float*)d_in[3];
  const float* w_k      = (const float*)d_in[4];
  const float* norm_h   = (const float*)d_in[5];
  const float* norm_k   = (const float*)d_in[6];
  const float* wcn      = (const float*)d_in[7];
  const float* cw       = (const float*)d_in[8];
  float* outp = (float*)d_out;
  char* ws = (char*)d_ws;

  // workspace layout (bytes)
  unsigned short* embb  = (unsigned short*)(ws + 0);          // 16,777,216
  unsigned short* Wb    = (unsigned short*)(ws + 16777216);   // 20,971,520
  unsigned short* value = (unsigned short*)(ws + 37748736);   // 33,554,432
  float*          skP   = (float*)(ws + 71303168);            // 8192*4*8*4 = 1,048,576
  float*          sdP   = (float*)(ws + 72351744);            // 1,048,576
  float*          shP   = (float*)(ws + 73400320);            // 1,048,576
  float*          gates = (float*)(ws + 74448896);            // 131,072
  float*          alphas= (float*)(ws + 74579968);            // 131,072 (end ~74.7MB)

  k_gather<<<NTOK, 256, 0, stream>>>(hash_idx, table, embb);
  k_cvtw<<<10240, 256, 0, stream>>>(w_v, w_k, Wb);
  dim3 gg(NGEMM / 256, NTOK / 256);  // (40, 32)
  k_gemm<<<gg, 512, 0, stream>>>(embb, Wb, hidden, norm_h, norm_k, value, skP, sdP, shP);
  k_alpha<<<NTOK, 256, 0, stream>>>(value, skP, sdP, shP, gates, alphas);
  k_final<<<(NTOK / 4) * 512 / 256, 256, 0, stream>>>(hidden, value, gates, alphas, wcn, cw, outp);
}

// Round 9
// 417.621 us; speedup vs baseline: 1.3390x; 1.0068x over previous
//
#include <hip/hip_runtime.h>
#include <hip/hip_bf16.h>

// Problem constants
#define BDIM 4
#define SDIM 2048
#define MDIM 4
#define DDIM 2048
#define EDIM 1024
#define NTOK 8192           // B*S
#define NGEMM 10240         // D + M*D
#define KDIM 1024           // E
#define NKT 16              // K-tiles of BK=64
#define NPAN 8              // 256-col panels per branch
#define EPS_GATE 1.1920929e-07f
#define EPS_CONV 1e-5f
#define RSQRT_D 0.022097086912079608f   // 1/sqrt(2048)

typedef __bf16 bf16x8 __attribute__((ext_vector_type(8)));
typedef float f32x4 __attribute__((ext_vector_type(4)));
typedef unsigned short ushort8 __attribute__((ext_vector_type(8)));

__constant__ int OFFS[8] = {0, 130003, 260024, 390051, 520094, 650145, 780202, 910271};

__device__ __forceinline__ float bf2f(unsigned short u) {
  union { unsigned int i; float f; } x; x.i = ((unsigned int)u) << 16; return x.f;
}
__device__ __forceinline__ unsigned short f2bf(float f) {
  __hip_bfloat16 h = __float2bfloat16(f);
  unsigned short u; __builtin_memcpy(&u, &h, 2); return u;
}

// ---------------- prep: gather (blocks 0..8191) + weight cvt (8192..18431) ---
__global__ __launch_bounds__(256) void k_prep(const int* __restrict__ idx,
                                              const float* __restrict__ table,
                                              const float* __restrict__ wv,
                                              const float* __restrict__ wk,
                                              unsigned short* __restrict__ embb,
                                              unsigned short* __restrict__ Wb) {
  const int bid = blockIdx.x;
  const int tid = threadIdx.x;
  if (bid < NTOK) {
    const int tok = bid;
    const int h = tid >> 5;
    const int e = (tid & 31) * 4;
    const int row = idx[tok * 8 + h] + OFFS[h];
    const float4 v = *(const float4*)(table + (size_t)row * 128 + e);
    ushort4 st;
    st.x = f2bf(v.x); st.y = f2bf(v.y); st.z = f2bf(v.z); st.w = f2bf(v.w);
    *(ushort4*)(embb + (size_t)tok * 1024 + h * 128 + e) = st;
  } else {
    const size_t i = ((size_t)(bid - NTOK) * 256 + tid) * 4;
    const size_t NV = (size_t)DDIM * EDIM;
    float4 v;
    if (i < NV) v = *(const float4*)(wv + i);
    else        v = *(const float4*)(wk + (i - NV));
    ushort4 st;
    st.x = f2bf(v.x); st.y = f2bf(v.y); st.z = f2bf(v.z); st.w = f2bf(v.w);
    *(ushort4*)(Wb + i) = st;
  }
}

// ---------------- GEMM: 256x256 tile, 8-phase counted-vmcnt + fused score ----
// T3+T4+T2+T1. Keys never stored (score reductions in epilogue via LDS-staged
// hidden). Value blocks also emit per-row sum(v^2) panel partials for k_alpha.
#define GLDS(g, l) __builtin_amdgcn_global_load_lds(                        \
    (const __attribute__((address_space(1))) void*)(g),                    \
    (__attribute__((address_space(3))) void*)(l), 16, 0, 0)

#define BARR() __builtin_amdgcn_s_barrier()
#define LGK0() asm volatile("s_waitcnt lgkmcnt(0)" ::: "memory")
#define VM6()  asm volatile("s_waitcnt vmcnt(6)" ::: "memory")
#define VM4()  asm volatile("s_waitcnt vmcnt(4)" ::: "memory")
#define VM2()  asm volatile("s_waitcnt vmcnt(2)" ::: "memory")
#define VM0()  asm volatile("s_waitcnt vmcnt(0)" ::: "memory")
#define SB0()  __builtin_amdgcn_sched_barrier(0)

__global__ __launch_bounds__(512, 1) void k_gemm(const unsigned short* __restrict__ A,
                                                 const unsigned short* __restrict__ Bw,
                                                 const float* __restrict__ hidden,
                                                 const float* __restrict__ norm_h,
                                                 const float* __restrict__ norm_k,
                                                 unsigned short* __restrict__ Cv,  // [8192][2048]
                                                 float* __restrict__ skP,          // [8192][4][8]
                                                 float* __restrict__ sdP,
                                                 float* __restrict__ shP,
                                                 float* __restrict__ svP)          // [8192][8]
{
  __shared__ __align__(1024) unsigned short lds[65536];  // A: [0,32768), B: [32768,65536)
  __shared__ float redk[2][128][4], redd[2][128][4], redh[2][128][4];  // 12KB
  const int tid = threadIdx.x;
  const int lane = tid & 63, wave = tid >> 6;
  const int wm = wave >> 2;          // 0..1
  const int wn = wave & 3;           // 0..3
  // T1: XCD-aware bijective block swizzle (nwg=1280, 1280%8==0)
  const int bid = blockIdx.y * gridDim.x + blockIdx.x;
  const int cpx = (gridDim.x * gridDim.y) >> 3;       // 160
  const int swz = (bid & 7) * cpx + (bid >> 3);
  const int row0 = (swz / gridDim.x) * 256;
  const int col0 = (swz % gridDim.x) * 256;
  const int lr = lane & 15;
  const int lg = lane >> 4;

  f32x4 acc[8][4] = {};
  bf16x8 aa[4][2];
  bf16x8 bb[4][2];

#define STG(src, rowbase, kt, gbase)                                           \
  { _Pragma("unroll") for (int l = 0; l < 2; ++l) {                            \
      const int cb = l * 512 + wave * 64;                                      \
      const int chunk = cb + lane;                                             \
      const int rr = chunk >> 3;                                               \
      const int cc = (chunk & 7) ^ (rr & 7);                                   \
      GLDS((src) + (size_t)((rowbase) + rr) * KDIM + (kt) * 64 + cc * 8,       \
           (char*)lds + (gbase) * 2 + cb * 16);                                \
  } }

#define LDA(gbase)                                                             \
  { _Pragma("unroll") for (int a = 0; a < 4; ++a)                              \
    _Pragma("unroll") for (int ks = 0; ks < 2; ++ks)                           \
      aa[a][ks] = *(const bf16x8*)(lds + (gbase) +                             \
          (wm * 64 + a * 16 + lr) * 64 + (((ks * 4 + lg) ^ (lr & 7)) * 8)); }

#define LDB(gbase, n0)                                                         \
  { _Pragma("unroll") for (int n = 0; n < 2; ++n)                              \
    _Pragma("unroll") for (int ks = 0; ks < 2; ++ks)                           \
      bb[(n0) + n][ks] = *(const bf16x8*)(lds + 32768 + (gbase) +              \
          (wn * 32 + n * 16 + lr) * 64 + (((ks * 4 + lg) ^ (lr & 7)) * 8)); }

#define MM(mfb, nfb)                                                           \
  { __builtin_amdgcn_s_setprio(1);                                             \
    _Pragma("unroll") for (int a = 0; a < 4; ++a)                              \
    _Pragma("unroll") for (int n = 0; n < 2; ++n)                              \
    _Pragma("unroll") for (int ks = 0; ks < 2; ++ks)                           \
      acc[(mfb) + a][(nfb) + n] = __builtin_amdgcn_mfma_f32_16x16x32_bf16(     \
          aa[a][ks], bb[(nfb) + n][ks], acc[(mfb) + a][(nfb) + n], 0, 0, 0);   \
    __builtin_amdgcn_s_setprio(0); }

  // ---- prologue ----
  STG(A,  row0 +   0, 0, 0 * 8192);
  STG(Bw, col0 +   0, 0, 32768 + 0 * 8192);
  STG(Bw, col0 + 128, 0, 32768 + 1 * 8192);
  STG(A,  row0 + 128, 0, 1 * 8192);
  STG(A,  row0 +   0, 1, 2 * 8192);
  STG(Bw, col0 +   0, 1, 32768 + 2 * 8192);
  STG(Bw, col0 + 128, 1, 32768 + 3 * 8192);
  VM6();
  BARR(); SB0();

  for (int kt = 0; kt < NKT; ++kt) {
    const int sA = (kt & 1) * 2;
    const int sN1 = ((kt + 1) & 1) * 2;
    // ---- P1 ----
    LDA(sA * 8192);
    LDB(sA * 8192, 0);
    if (kt + 1 < NKT) STG(A, row0 + 128, kt + 1, (sN1 + 1) * 8192);
    if (kt == NKT - 1) { VM2(); }        // tail: complete B1(15) for P2(15)
    BARR(); LGK0(); SB0();
    MM(0, 0);
    BARR(); SB0();
    // ---- P2 ----
    LDB((sA + 1) * 8192, 2);
    if (kt + 2 < NKT) STG(A, row0 + 0, kt + 2, sA * 8192);
    if (kt == NKT - 1) { VM0(); }        // tail: complete A1(15) for P3(15)
    BARR(); LGK0(); SB0();
    MM(0, 2);
    BARR(); SB0();
    // ---- P3 ----
    LDA((sA + 1) * 8192);
    if (kt + 2 < NKT) STG(Bw, col0 + 0, kt + 2, 32768 + sA * 8192);
    BARR(); LGK0(); SB0();
    MM(4, 2);
    BARR(); SB0();
    // ---- P4 ----
    if (kt + 2 < NKT) STG(Bw, col0 + 128, kt + 2, 32768 + (sA + 1) * 8192);
    if (kt <= NKT - 3)      { VM6(); }   // steady: 3 granules stay in flight
    else if (kt == NKT - 2) { VM4(); }   // tail: complete A0(15),B0(15)
    BARR(); LGK0(); SB0();
    MM(4, 0);
    BARR(); SB0();
  }

  if (col0 < DDIM) {
    // ---- value block: store bf16 + per-row sum(v^2) panel partials ----
    const int pan = col0 >> 8;
#pragma unroll
    for (int mf = 0; mf < 8; ++mf) {
#pragma unroll
      for (int nf = 0; nf < 4; ++nf) {
        const int grow = row0 + (mf >> 2) * 128 + wm * 64 + (mf & 3) * 16 + (lane >> 4) * 4;
        const int gcol = col0 + (nf >> 1) * 128 + wn * 32 + (nf & 1) * 16 + lr;
        unsigned short* p = Cv + (size_t)grow * DDIM + gcol;
#pragma unroll
        for (int r = 0; r < 4; ++r) p[(size_t)r * DDIM] = f2bf(acc[mf][nf][r]);
      }
    }
#pragma unroll
    for (int h = 0; h < 2; ++h) {
#pragma unroll
      for (int mf = 0; mf < 4; ++mf) {
#pragma unroll
        for (int r = 0; r < 4; ++r) {
          const int rl = wm * 64 + mf * 16 + (lane >> 4) * 4 + r;
          const int amf = h * 4 + mf;
          float pv = 0.f;
#pragma unroll
          for (int nf = 0; nf < 4; ++nf) {
            const float v = acc[amf][nf][r]; pv += v * v;
          }
#pragma unroll
          for (int off = 1; off < 16; off <<= 1) pv += __shfl_xor(pv, off);
          if (lr == 0) redk[h][rl][wn] = pv;
        }
      }
    }
    BARR();
    if (tid < 256) {
      const int h = tid >> 7, rl = tid & 127;
      const int tok = row0 + h * 128 + rl;
      svP[(size_t)tok * NPAN + pan] =
          redk[h][rl][0] + redk[h][rl][1] + redk[h][rl][2] + redk[h][rl][3];
    }
  } else {
    // ---- keys block: fused score reductions via LDS-staged hidden ----
    const int m = (col0 - DDIM) >> 11;
    const int dbase = (col0 - DDIM) & (DDIM - 1);
    const int pan = dbase >> 8;
    float* hl = (float*)lds;                       // 128 x 256 fp32 = 128KB
    float wkh[4];
#pragma unroll
    for (int nf = 0; nf < 4; ++nf) {
      const int cl = (nf >> 1) * 128 + wn * 32 + (nf & 1) * 16 + lr;
      wkh[nf] = norm_k[m * DDIM + dbase + cl] * norm_h[m * DDIM + dbase + cl];
    }
#pragma unroll
    for (int h = 0; h < 2; ++h) {
      BARR();  // previous half's hl reads (or main-loop LDS reads) complete
#pragma unroll
      for (int i = 0; i < 16; ++i) {
        const int idx = i * 512 + tid;             // float4 index (8192 total)
        const int rl = idx >> 6;
        const int c4 = idx & 63;
        ((float4*)hl)[idx] = *(const float4*)(hidden +
            ((size_t)(row0 + h * 128 + rl) * 4 + m) * DDIM + dbase + c4 * 4);
      }
      BARR();
#pragma unroll
      for (int mf = 0; mf < 4; ++mf) {
#pragma unroll
        for (int r = 0; r < 4; ++r) {
          const int rl = wm * 64 + mf * 16 + (lane >> 4) * 4 + r;
          const int amf = h * 4 + mf;
          float pk = 0.f, pd = 0.f, ph = 0.f;
#pragma unroll
          for (int nf = 0; nf < 4; ++nf) {
            const int cl = (nf >> 1) * 128 + wn * 32 + (nf & 1) * 16 + lr;
            const float kv = acc[amf][nf][r];
            const float hv = hl[rl * 256 + cl];
            pk += kv * kv; ph += hv * hv; pd += kv * hv * wkh[nf];
          }
#pragma unroll
          for (int off = 1; off < 16; off <<= 1) {
            pk += __shfl_xor(pk, off);
            pd += __shfl_xor(pd, off);
            ph += __shfl_xor(ph, off);
          }
          if (lr == 0) {
            redk[h][rl][wn] = pk; redd[h][rl][wn] = pd; redh[h][rl][wn] = ph;
          }
        }
      }
    }
    BARR();
    if (tid < 256) {
      const int h = tid >> 7, rl = tid & 127;
      const int tok = row0 + h * 128 + rl;
      const size_t pidx = ((size_t)tok * 4 + m) * NPAN + pan;
      skP[pidx] = redk[h][rl][0] + redk[h][rl][1] + redk[h][rl][2] + redk[h][rl][3];
      sdP[pidx] = redd[h][rl][0] + redd[h][rl][1] + redd[h][rl][2] + redd[h][rl][3];
      shP[pidx] = redh[h][rl][0] + redh[h][rl][1] + redh[h][rl][2] + redh[h][rl][3];
    }
  }
}

// ---------------- alpha/gate: combine partials (no value read) ---------------
__global__ __launch_bounds__(256) void k_alpha(const float* __restrict__ skP,
                                               const float* __restrict__ sdP,
                                               const float* __restrict__ shP,
                                               const float* __restrict__ svP,
                                               float* __restrict__ gates,
                                               float* __restrict__ alphas) {
  const int idx = blockIdx.x * 256 + threadIdx.x;   // tok*4 + m (0..32767)
  const int tok = idx >> 2;
  const size_t base = (size_t)idx * NPAN;
  float sk = 0.f, sd = 0.f, sh = 0.f, sv = 0.f;
#pragma unroll
  for (int q = 0; q < NPAN; ++q) {
    sk += skP[base + q]; sd += sdP[base + q]; sh += shP[base + q];
    sv += svP[(size_t)tok * NPAN + q];
  }
  const float msv = sv * (1.f / 2048.f);
  const float msk = sk * (1.f / 2048.f) + EPS_GATE;
  const float msh = sh * (1.f / 2048.f) + EPS_GATE;
  const float score = sd * rsqrtf(msk) * rsqrtf(msh) * RSQRT_D;
  const float sgn = (score > 0.f) ? 1.f : ((score < 0.f) ? -1.f : 0.f);
  const float gg = sqrtf(fmaxf(fabsf(score), 1e-6f)) * sgn;
  const float gate = 1.f / (1.f + expf(-gg));
  gates[idx] = gate;
  alphas[idx] = gate * rsqrtf(gate * gate * msv + EPS_CONV);
}

// ---------------- final: thread owns (4-token group, d4); cw regs reused -----
__global__ __launch_bounds__(256) void k_final(const float* __restrict__ hidden,
                                               const unsigned short* __restrict__ valueb,
                                               const float* __restrict__ gates,
                                               const float* __restrict__ alphas,
                                               const float* __restrict__ wcn,
                                               const float* __restrict__ cw,   // [M*D][4]
                                               float* __restrict__ outp) {
  const int lin = blockIdx.x * 256 + threadIdx.x;   // (grp, d4)
  const int d4 = lin & 511;
  const int grp = lin >> 9;
  const int tokbase = grp * 4;          // groups never cross sequence bounds
  const int sbase = tokbase & (SDIM - 1);
  const int d = d4 * 4;

  // 13 distinct tap rows: tokbase-9 .. tokbase+3  (ri = t - 3j + 9)
  float4 vrow[13];
#pragma unroll
  for (int ri = 0; ri < 13; ++ri) {
    const int off = ri - 9;
    if (sbase + off >= 0) {
      const ushort4 u = *(const ushort4*)(valueb + (size_t)(tokbase + off) * DDIM + d);
      vrow[ri] = make_float4(bf2f(u.x), bf2f(u.y), bf2f(u.z), bf2f(u.w));
    } else vrow[ri] = make_float4(0.f, 0.f, 0.f, 0.f);
  }

#pragma unroll
  for (int m = 0; m < 4; ++m) {
    float cwr[4][4];
#pragma unroll
    for (int i = 0; i < 4; ++i)
      *(float4*)cwr[i] = *(const float4*)(cw + (size_t)(m * DDIM + d + i) * 4);
    const float4 wn = *(const float4*)(wcn + m * DDIM + d);
    float al[13];
#pragma unroll
    for (int ri = 0; ri < 13; ++ri) {
      const int off = ri - 9;
      al[ri] = (sbase + off >= 0) ? alphas[(tokbase + off) * 4 + m] : 0.f;
    }
#pragma unroll
    for (int t = 0; t < 4; ++t) {
      const int tok = tokbase + t;
      const float g = gates[tok * 4 + m];
      const float4 h4 = *(const float4*)(hidden + ((size_t)tok * 4 + m) * DDIM + d);
      float cx = 0.f, cy = 0.f, cz = 0.f, cv = 0.f;
#pragma unroll
      for (int j = 0; j < 4; ++j) {
        const int ri = t + 9 - 3 * j;
        const float aj = al[ri];
        const int tt = 3 - j;
        cx += cwr[0][tt] * aj * vrow[ri].x;
        cy += cwr[1][tt] * aj * vrow[ri].y;
        cz += cwr[2][tt] * aj * vrow[ri].z;
        cv += cwr[3][tt] * aj * vrow[ri].w;
      }
      cx *= wn.x; cy *= wn.y; cz *= wn.z; cv *= wn.w;
      cx = cx / (1.f + expf(-cx));
      cy = cy / (1.f + expf(-cy));
      cz = cz / (1.f + expf(-cz));
      cv = cv / (1.f + expf(-cv));
      const int ri0 = t + 9;
      float4 o;
      o.x = h4.x + g * vrow[ri0].x + cx;
      o.y = h4.y + g * vrow[ri0].y + cy;
      o.z = h4.z + g * vrow[ri0].z + cz;
      o.w = h4.w + g * vrow[ri0].w + cv;
      *(float4*)(outp + ((size_t)tok * 4 + m) * DDIM + d) = o;
    }
  }
}

// ---------------- launcher ---------------------------------------------------
extern "C" void kernel_launch(void* const* d_in, const int* in_sizes, int n_in,
                              void* d_out, int out_size, void* d_ws, size_t ws_size,
                              hipStream_t stream) {
  const int*   hash_idx = (const int*)d_in[0];
  const float* hidden   = (const float*)d_in[1];
  const float* table    = (const float*)d_in[2];
  const float* w_v      = (const float*)d_in[3];
  const float* w_k      = (const float*)d_in[4];
  const float* norm_h   = (const float*)d_in[5];
  const float* norm_k   = (const float*)d_in[6];
  const float* wcn      = (const float*)d_in[7];
  const float* cw       = (const float*)d_in[8];
  float* outp = (float*)d_out;
  char* ws = (char*)d_ws;

  // workspace layout (bytes)
  unsigned short* embb  = (unsigned short*)(ws + 0);          // 16,777,216
  unsigned short* Wb    = (unsigned short*)(ws + 16777216);   // 20,971,520
  unsigned short* value = (unsigned short*)(ws + 37748736);   // 33,554,432
  float*          skP   = (float*)(ws + 71303168);            // 8192*4*8*4 = 1,048,576
  float*          sdP   = (float*)(ws + 72351744);            // 1,048,576
  float*          shP   = (float*)(ws + 73400320);            // 1,048,576
  float*          svP   = (float*)(ws + 74448896);            // 8192*8*4 = 262,144
  float*          gates = (float*)(ws + 74711040);            // 131,072
  float*          alphas= (float*)(ws + 74842112);            // 131,072 (end ~75MB)

  k_prep<<<NTOK + 10240, 256, 0, stream>>>(hash_idx, table, w_v, w_k, embb, Wb);
  dim3 gg(NGEMM / 256, NTOK / 256);  // (40, 32)
  k_gemm<<<gg, 512, 0, stream>>>(embb, Wb, hidden, norm_h, norm_k, value,
                                 skP, sdP, shP, svP);
  k_alpha<<<NTOK * MDIM / 256, 256, 0, stream>>>(skP, sdP, shP, svP, gates, alphas);
  k_final<<<(NTOK / 4) * 512 / 256, 256, 0, stream>>>(hidden, value, gates, alphas, wcn, cw, outp);
}